// Round 13
// baseline (182.924 us; speedup 1.0000x reference)
//
#include <hip/hip_runtime.h>

// B=4, C=512, L=2048, H=8, D=64. f32 inputs, f32 output.
// Universal fragment-packed layouts (r4); r11 store coalescing; r12 XCD-reuse
// swizzle for GEMMs (-8us). attn: r5 structure, 66.5us stable.
// r13: *** (a) MEASUREMENT: attn split into 2 dispatches (bh halves, ~34us
// each) so producers >34us finally surface in the top-5 (6 rounds of blind
// pool-guessing ends here). (b) outgemm TLP: 2048 waves = 2/SIMD was the same
// latency-bound residency that capped attn; wave tile 32x64 -> 32x32, grid
// 512 -> 1024 blocks = 4/SIMD (VGPR ~70, no cap). wg%8 = ly%8 keeps aoP
// l-slice sharers co-XCD. ***

#define LDIM 2048
#define CDIM 512
#define BATCH 4

typedef __attribute__((ext_vector_type(8))) short s16x8;
typedef __attribute__((ext_vector_type(4))) float f32x4;
typedef __attribute__((ext_vector_type(4))) unsigned short u16x4;
typedef unsigned int u32;
typedef unsigned short u16;

__device__ __forceinline__ u16 f2b(float f) {
    unsigned u = __float_as_uint(f);
    u += 0x7fffu + ((u >> 16) & 1u);   // RNE
    return (u16)(u >> 16);
}
// pack two floats -> two bf16 (round-half-up) in one u32 (b in high half)
__device__ __forceinline__ u32 pk2(float a, float b) {
    u32 ua = __float_as_uint(a) + 0x8000u;
    u32 ub = __float_as_uint(b) + 0x8000u;
    return __builtin_amdgcn_perm(ub, ua, 0x07060302u);  // {ub.hi16, ua.hi16}
}

// ---------------- unified transpose + f32->bf16 convert -> packed chunks -------
__global__ __launch_bounds__(256)
void transpA_k(const float* __restrict__ x, const float* __restrict__ wq,
               const float* __restrict__ wo, u16* __restrict__ XP,
               u16* __restrict__ WP, u16* __restrict__ WOP)
{
    const int r0 = blockIdx.x * 64;
    const int y  = blockIdx.y;
    const float* in; u16* out; int inLD, c0;
    if (y < 128) {
        const int b = y >> 5, ct = y & 31;
        in = x + (size_t)b * CDIM * LDIM; inLD = LDIM; c0 = ct * 64;
        out = XP + (size_t)b * LDIM * CDIM;
    } else if (y < 152) {
        in = wq; inLD = 1536; c0 = (y - 128) * 64; out = WP;
    } else {
        in = wo; inLD = 512;  c0 = (y - 152) * 64; out = WOP;
    }

    __shared__ __align__(16) u16 t[64][80];
    const int tt = threadIdx.x;
    const int lr = tt >> 4, lc = (tt & 15) * 4;
    #pragma unroll
    for (int i = 0; i < 4; ++i) {
        f32x4 v = *(const f32x4*)(in + (size_t)(r0 + lr + i * 16) * inLD + c0 + lc);
        #pragma unroll
        for (int j = 0; j < 4; ++j) t[lc + j][lr + i * 16] = f2b(v[j]);
    }
    __syncthreads();
    // coalesced packed store: wave wvx writes chunk cidx = s*4+wvx contiguously
    const int lane = tt & 63;
    const int wvx = tt >> 6;
    const int qq = lane >> 4, mnq = lane & 15;
    #pragma unroll
    for (int s = 0; s < 2; ++s) {
        const int cidx = s * 4 + wvx;            // 0..7
        const int rt = cidx >> 1, cs = cidx & 1;
        s16x8 v = *(const s16x8*)&t[rt * 16 + mnq][cs * 32 + qq * 8];
        const int slot = ((c0 >> 4) + rt) * 16 + (r0 >> 5) + cs;
        *(s16x8*)(out + (size_t)slot * 512 + lane * 8) = v;
    }
}

// ---------------- QKV GEMM (r12): packed loads; LDS-staged stores; XCD swizzle -
__global__ __launch_bounds__(256)
void qkvgemm_bf16(const u16* __restrict__ XP, const u16* __restrict__ WP,
                  u16* __restrict__ QF, u16* __restrict__ KF, u16* __restrict__ VF)
{
    const int wg = blockIdx.x;
    const int xf = wg >> 6;              // 0..23
    const int yz = wg & 63;              // b*16 + y
    const int b  = yz >> 4;
    const int l0 = (yz & 15) * 128;
    const int f0 = xf * 64;
    const u16* xTb = XP + (size_t)b * LDIM * CDIM;
    const int t = threadIdx.x, w = t >> 6, lane = t & 63;
    const int mn = lane & 15, q = lane >> 4;
    const bool vpart = (f0 >= 1024);

    const u16 *Abase, *Bbase;
    int mbase, nbase;
    if (!vpart) {
        mbase = f0 + (w >> 1) * 32; nbase = l0 + (w & 1) * 64;
        Abase = WP + (size_t)mbase * CDIM; Bbase = xTb + (size_t)nbase * CDIM;
    } else {
        mbase = l0 + w * 32; nbase = f0;
        Abase = xTb + (size_t)mbase * CDIM; Bbase = WP + (size_t)nbase * CDIM;
    }

    f32x4 acc[2][4] = {};
    #pragma unroll 2
    for (int c0 = 0; c0 < CDIM; c0 += 32) {
        s16x8 a[2], bf[4];
        #pragma unroll
        for (int mi = 0; mi < 2; ++mi)
            a[mi] = *(const s16x8*)(Abase + mi * 16 * CDIM + c0 * 16 + lane * 8);
        #pragma unroll
        for (int ni = 0; ni < 4; ++ni)
            bf[ni] = *(const s16x8*)(Bbase + ni * 16 * CDIM + c0 * 16 + lane * 8);
        #pragma unroll
        for (int mi = 0; mi < 2; ++mi)
            #pragma unroll
            for (int ni = 0; ni < 4; ++ni)
                acc[mi][ni] = __builtin_amdgcn_mfma_f32_16x16x32_bf16(a[mi], bf[ni], acc[mi][ni], 0, 0, 0);
    }

    __shared__ __align__(16) u16 stg[8192];      // 16KB staging tile

    if (!vpart) {
        const int part = f0 >> 9;
        const float sc2 = (part == 0) ? 0.18033688f : 1.0f;  // 0.125*log2(e)
        #pragma unroll
        for (int mi = 0; mi < 2; ++mi) {
            const int fg0 = mbase + mi * 16;
            const int d0 = (fg0 & 63) + q * 4;          // 4-aligned d base
            const int kd = d0 >> 5, qq = (d0 >> 3) & 3, e0 = d0 & 7;
            #pragma unroll
            for (int ni = 0; ni < 4; ++ni) {
                const int lg = nbase + ni * 16 + mn;     // L index
                int addr;
                if (part == 0) {                         // QF[t16][kd][lane][8], local
                    const int t16l = (lg & 127) >> 4, mnq = lg & 15;
                    addr = (t16l * 2 + kd) * 512 + (qq * 16 + mnq) * 8 + e0;
                } else {                                 // KF[j64][jt][kd][lane][8], kperm absorbed
                    const int j64l = (lg & 127) >> 6, r6 = lg & 63;
                    const int jt  = ((r6 >> 2) & 1) * 2 + (r6 >> 5);
                    const int mnk = ((r6 >> 3) & 3) * 4 + (r6 & 3);
                    addr = ((j64l * 4 + jt) * 2 + kd) * 512 + (qq * 16 + mnk) * 8 + e0;
                }
                u16x4 pk;
                #pragma unroll
                for (int r = 0; r < 4; ++r) pk[r] = f2b(acc[mi][ni][r] * sc2);
                *(u16x4*)(stg + addr) = pk;
            }
        }
    } else {
        #pragma unroll
        for (int ni = 0; ni < 4; ++ni) {
            const int fg = nbase + ni * 16 + mn;
            const int d = fg & 63;
            const int dt = d >> 4, mnv = d & 15;
            #pragma unroll
            for (int mi = 0; mi < 2; ++mi) {
                const int lg0 = mbase + mi * 16 + q * 4;    // 4-aligned j base
                const int j64l = (lg0 & 127) >> 6, j6 = lg0 & 63;
                const int kj = j6 >> 5, qq = (j6 >> 3) & 3, e0 = j6 & 7;
                const int addr = ((j64l * 2 + kj) * 4 + dt) * 512 + (qq * 16 + mnv) * 8 + e0;
                u16x4 pk;
                #pragma unroll
                for (int r = 0; r < 4; ++r) pk[r] = f2b(acc[mi][ni][r]);
                *(u16x4*)(stg + addr) = pk;
            }
        }
    }

    __syncthreads();
    // linear copy: 4 x (256 threads x 16B) = 16KB, each wave 1KB contiguous
    const int h = (f0 >> 6) & 7;
    const size_t bhoff = (size_t)(b * 8 + h) * LDIM * 64;
    u16* T;
    if (!vpart) {
        const int part = f0 >> 9;
        T = ((part == 0) ? QF + bhoff + (size_t)(l0 >> 4) * 1024
                         : KF + bhoff + (size_t)(l0 >> 6) * 4096);
    } else {
        T = VF + bhoff + (size_t)(l0 >> 6) * 4096;
    }
    #pragma unroll
    for (int it = 0; it < 4; ++it)
        *(s16x8*)(T + it * 2048 + t * 8) = *(const s16x8*)(stg + it * 2048 + t * 8);
}

// ---------------- Flash attention (r5 structure), bh-split dispatches ----------
// grid (x=bh-half 16, y=32), 128 threads (2 waves). bx%8 = bh%8: XCD-pinned.
__global__ __launch_bounds__(128)
void attn_k(const u16* __restrict__ QF, const u16* __restrict__ KF,
            const u16* __restrict__ VF, u16* __restrict__ aoP, int bh0)
{
    const int bh = bh0 + blockIdx.x;
    const int b = bh >> 3, h = bh & 7;
    const u16* Qh = QF + (size_t)bh * LDIM * 64;
    const u16* Kh = KF + (size_t)bh * LDIM * 64;
    const u16* Vh = VF + (size_t)bh * LDIM * 64;

    __shared__ __align__(16) float o_sh[64][68];   // +4 pad (2-way = free)
    __shared__ float lp_sh[64];

    const int tid = threadIdx.x;
    const int wv = tid >> 6;
    const int lane = tid & 63;
    const int mn = lane & 15, q = lane >> 4;
    const int ib64 = blockIdx.y;         // 64-row i-block
    const int TH = 16;                   // j-tiles per wave (of 32 total)
    const int tbase = wv * TH;

    s16x8 aq[4][2];
    #pragma unroll
    for (int ibt = 0; ibt < 4; ++ibt) {
        const int t16 = ib64 * 4 + ibt;
        #pragma unroll
        for (int kd = 0; kd < 2; ++kd)
            aq[ibt][kd] = *(const s16x8*)(Qh + (size_t)((t16 * 2 + kd) * 512) + lane * 8);
    }

    f32x4 o_acc[4][4] = {};
    float lp[4] = {0.f, 0.f, 0.f, 0.f};

    // preload this wave's tile-0 K/V fragments (fully coalesced)
    s16x8 kc[2][4], vc[2][4];
    {
        const u16* Kt = Kh + (size_t)tbase * 4096;
        const u16* Vt = Vh + (size_t)tbase * 4096;
        #pragma unroll
        for (int kd = 0; kd < 2; ++kd)
            #pragma unroll
            for (int jt = 0; jt < 4; ++jt)
                kc[kd][jt] = *(const s16x8*)(Kt + ((jt * 2 + kd) << 9) + (lane << 3));
        #pragma unroll
        for (int kj = 0; kj < 2; ++kj)
            #pragma unroll
            for (int dt = 0; dt < 4; ++dt)
                vc[kj][dt] = *(const s16x8*)(Vt + ((kj * 4 + dt) << 9) + (lane << 3));
    }

    #pragma unroll 2
    for (int jj = 0; jj < TH; ++jj) {
        const int tn = tbase + ((jj + 1) & (TH - 1));   // last iter wraps (L2-hot)
        const u16* Kt = Kh + (size_t)tn * 4096;
        const u16* Vt = Vh + (size_t)tn * 4096;

        // issue next tile's K loads FIRST
        s16x8 kn[2][4];
        #pragma unroll
        for (int kd = 0; kd < 2; ++kd)
            #pragma unroll
            for (int jt = 0; jt < 4; ++jt)
                kn[kd][jt] = *(const s16x8*)(Kt + ((jt * 2 + kd) << 9) + (lane << 3));

        // S^T = K.Q^T on current K: 32 MFMA (4 ibt)
        f32x4 s[4][4] = {};
        #pragma unroll
        for (int kd = 0; kd < 2; ++kd)
            #pragma unroll
            for (int jt = 0; jt < 4; ++jt)
                #pragma unroll
                for (int ibt = 0; ibt < 4; ++ibt)
                    s[ibt][jt] = __builtin_amdgcn_mfma_f32_16x16x32_bf16(kc[kd][jt], aq[ibt][kd], s[ibt][jt], 0, 0, 0);

        // issue next tile's V loads AFTER QK (staggered: caps VGPR peak)
        s16x8 vn[2][4];
        #pragma unroll
        for (int kj = 0; kj < 2; ++kj)
            #pragma unroll
            for (int dt = 0; dt < 4; ++dt)
                vn[kj][dt] = *(const s16x8*)(Vt + ((kj * 4 + dt) << 9) + (lane << 3));

        // p = 2^s; build PV B-fragments fully in-register (lane-local j-slots).
        #pragma unroll
        for (int kj = 0; kj < 2; ++kj) {
            s16x8 ap[4];
            #pragma unroll
            for (int ibt = 0; ibt < 4; ++ibt) {
                float pa0 = __builtin_amdgcn_exp2f(s[ibt][kj][0]);
                float pa1 = __builtin_amdgcn_exp2f(s[ibt][kj][1]);
                float pa2 = __builtin_amdgcn_exp2f(s[ibt][kj][2]);
                float pa3 = __builtin_amdgcn_exp2f(s[ibt][kj][3]);
                float pb0 = __builtin_amdgcn_exp2f(s[ibt][kj + 2][0]);
                float pb1 = __builtin_amdgcn_exp2f(s[ibt][kj + 2][1]);
                float pb2 = __builtin_amdgcn_exp2f(s[ibt][kj + 2][2]);
                float pb3 = __builtin_amdgcn_exp2f(s[ibt][kj + 2][3]);
                lp[ibt] += ((pa0 + pa1) + (pa2 + pa3)) + ((pb0 + pb1) + (pb2 + pb3));
                union { s16x8 v; u32 w[4]; } u;
                u.w[0] = pk2(pa0, pa1);
                u.w[1] = pk2(pa2, pa3);
                u.w[2] = pk2(pb0, pb1);
                u.w[3] = pk2(pb2, pb3);
                ap[ibt] = u.v;
            }
            #pragma unroll
            for (int dt = 0; dt < 4; ++dt)
                #pragma unroll
                for (int ibt = 0; ibt < 4; ++ibt)
                    o_acc[ibt][dt] = __builtin_amdgcn_mfma_f32_16x16x32_bf16(vc[kj][dt], ap[ibt], o_acc[ibt][dt], 0, 0, 0);
        }

        // rotate prefetched registers
        #pragma unroll
        for (int kd = 0; kd < 2; ++kd)
            #pragma unroll
            for (int jt = 0; jt < 4; ++jt)
                kc[kd][jt] = kn[kd][jt];
        #pragma unroll
        for (int kj = 0; kj < 2; ++kj)
            #pragma unroll
            for (int dt = 0; dt < 4; ++dt)
                vc[kj][dt] = vn[kj][dt];
    }

    #pragma unroll
    for (int ibt = 0; ibt < 4; ++ibt) {
        lp[ibt] += __shfl_xor(lp[ibt], 16);
        lp[ibt] += __shfl_xor(lp[ibt], 32);
    }

    // combine the two waves' j-partials: plain addition (sum-normalized softmax)
    if (wv == 1) {
        #pragma unroll
        for (int ibt = 0; ibt < 4; ++ibt) {
            #pragma unroll
            for (int dt = 0; dt < 4; ++dt)
                *(f32x4*)&o_sh[ibt * 16 + mn][dt * 16 + q * 4] = o_acc[ibt][dt];
            if (q == 0) lp_sh[ibt * 16 + mn] = lp[ibt];
        }
    }
    __syncthreads();
    if (wv == 0) {
        u16* Ab = aoP + (size_t)b * LDIM * 512;
        #pragma unroll
        for (int ibt = 0; ibt < 4; ++ibt) {
            const float rinv = 1.0f / (lp[ibt] + lp_sh[ibt * 16 + mn]);
            const int ltile = ib64 * 4 + ibt;
            #pragma unroll
            for (int dt = 0; dt < 4; ++dt) {
                f32x4 os = *(const f32x4*)&o_sh[ibt * 16 + mn][dt * 16 + q * 4];
                u16x4 pk;
                #pragma unroll
                for (int r = 0; r < 4; ++r)
                    pk[r] = f2b((o_acc[ibt][dt][r] + os[r]) * rinv);
                // packed-chunk store: col = h*64 + dt*16 + q*4 + r
                const int cstep = h * 2 + (dt >> 1);
                const int lanep = ((dt & 1) * 2 + (q >> 1)) * 16 + mn;
                u16* dst = Ab + ((size_t)(ltile * 16 + cstep) * 64 + lanep) * 8 + (q & 1) * 4;
                *(u16x4*)dst = pk;
            }
        }
    }
}

// ---------------- Output GEMM: 32x32 wave tiles (4/SIMD TLP) + XCD swizzle -----
// 1-D grid 1024: wg = xf*128 + (b*32+ly) -> wg%8 = ly%8: aoP sharers co-XCD.
__global__ __launch_bounds__(256)
void outgemm_d(const u16* __restrict__ aoP, const u16* __restrict__ WOP,
               const float* __restrict__ bias, float* __restrict__ Y)
{
    const int wg = blockIdx.x;
    const int xf = wg >> 7;              // 0..7
    const int yz = wg & 127;             // b*32 + ly
    const int b  = yz >> 5;
    const int l0 = (yz & 31) * 64;
    const int f0 = xf * 64;
    const int t = threadIdx.x, w = t >> 6, lane = t & 63;
    const int mn = lane & 15, q = lane >> 4;
    const int mbase = f0 + (w >> 1) * 32;
    const int nbase = l0 + (w & 1) * 32;
    const u16* Abase = WOP + (size_t)mbase * CDIM;
    const u16* Bbase = aoP + ((size_t)b * LDIM + nbase) * CDIM;
    float* Yb = Y + (size_t)b * CDIM * LDIM;

    f32x4 acc[2][2] = {};
    #pragma unroll 2
    for (int c0 = 0; c0 < CDIM; c0 += 32) {
        s16x8 a[2], bf[2];
        #pragma unroll
        for (int mi = 0; mi < 2; ++mi)
            a[mi] = *(const s16x8*)(Abase + mi * 16 * CDIM + c0 * 16 + lane * 8);
        #pragma unroll
        for (int ni = 0; ni < 2; ++ni)
            bf[ni] = *(const s16x8*)(Bbase + ni * 16 * CDIM + c0 * 16 + lane * 8);
        #pragma unroll
        for (int mi = 0; mi < 2; ++mi)
            #pragma unroll
            for (int ni = 0; ni < 2; ++ni)
                acc[mi][ni] = __builtin_amdgcn_mfma_f32_16x16x32_bf16(a[mi], bf[ni], acc[mi][ni], 0, 0, 0);
    }
    #pragma unroll
    for (int mi = 0; mi < 2; ++mi)
        #pragma unroll
        for (int r = 0; r < 4; ++r) {
            const int f = mbase + mi * 16 + q * 4 + r;
            const float bs = bias[f];
            #pragma unroll
            for (int ni = 0; ni < 2; ++ni)
                Yb[(size_t)f * LDIM + nbase + ni * 16 + mn] = acc[mi][ni][r] + bs;
        }
}

extern "C" void kernel_launch(void* const* d_in, const int* in_sizes, int n_in,
                              void* d_out, int out_size, void* d_ws, size_t ws_size,
                              hipStream_t stream) {
    const float *x = nullptr, *w_qkv = nullptr, *w_out = nullptr, *b_out = nullptr;
    for (int i = 0; i < n_in; ++i) {
        switch (in_sizes[i]) {
            case 4 * 512 * 2048: x     = (const float*)d_in[i]; break;
            case 512 * 1536:     w_qkv = (const float*)d_in[i]; break;
            case 512 * 512:      w_out = (const float*)d_in[i]; break;
            case 512:            b_out = (const float*)d_in[i]; break;
        }
    }
    float* out = (float*)d_out;                 // [4][512][2048] f32

    const size_t SLAB = (size_t)BATCH * LDIM * 512;      // 4194304 elems
    u16* WOP = (u16*)d_ws;                               // [512 rows][512] packed
    u16* XP  = WOP + (size_t)512 * 512;                  // [4][2048 rows][512] packed
    u16* WP  = XP + SLAB;                                // [1536 rows][512] packed
    u16* QF  = WP + (size_t)1536 * 512;                  // [32][2048*64] attn-packed
    u16* KF  = QF + SLAB;                                // [32][2048*64] attn-packed
    u16* VF  = KF + SLAB;                                // [32][2048*64] attn-packed
    u16* aoP = VF + SLAB;                                // [4][2048 rows][512] packed

    transpA_k<<<dim3(8, 160), 256, 0, stream>>>(x, w_qkv, w_out, XP, WP, WOP);
    qkvgemm_bf16<<<dim3(1536), 256, 0, stream>>>(XP, WP, QF, KF, VF);
    attn_k<<<dim3(16, 32), 128, 0, stream>>>(QF, KF, VF, aoP, 0);
    attn_k<<<dim3(16, 32), 128, 0, stream>>>(QF, KF, VF, aoP, 16);
    outgemm_d<<<dim3(1024), 256, 0, stream>>>(aoP, WOP, b_out, out);
}

// Round 14
// 171.251 us; speedup vs baseline: 1.0682x; 1.0682x over previous
//
#include <hip/hip_runtime.h>

// B=4, C=512, L=2048, H=8, D=64. f32 inputs, f32 output.
// Universal fragment-packed layouts (r4); r11 store coalescing; r12 XCD-reuse
// swizzle for GEMMs. attn: r5 structure (66.5us, single dispatch — r13's split
// showed halves DON'T scale: 2x50us serialized; reverted).
// r14: *** recombine proven bests: single-dispatch attn (r12) + r13's outgemm
// 32x32 wave tiles (2->4 waves/SIMD; r13 subtraction showed pool dropped
// 103->77us = outgemm -25us, the TLP win attn couldn't have). ***

#define LDIM 2048
#define CDIM 512
#define BATCH 4

typedef __attribute__((ext_vector_type(8))) short s16x8;
typedef __attribute__((ext_vector_type(4))) float f32x4;
typedef __attribute__((ext_vector_type(4))) unsigned short u16x4;
typedef unsigned int u32;
typedef unsigned short u16;

__device__ __forceinline__ u16 f2b(float f) {
    unsigned u = __float_as_uint(f);
    u += 0x7fffu + ((u >> 16) & 1u);   // RNE
    return (u16)(u >> 16);
}
// pack two floats -> two bf16 (round-half-up) in one u32 (b in high half)
__device__ __forceinline__ u32 pk2(float a, float b) {
    u32 ua = __float_as_uint(a) + 0x8000u;
    u32 ub = __float_as_uint(b) + 0x8000u;
    return __builtin_amdgcn_perm(ub, ua, 0x07060302u);  // {ub.hi16, ua.hi16}
}

// ---------------- unified transpose + f32->bf16 convert -> packed chunks -------
__global__ __launch_bounds__(256)
void transpA_k(const float* __restrict__ x, const float* __restrict__ wq,
               const float* __restrict__ wo, u16* __restrict__ XP,
               u16* __restrict__ WP, u16* __restrict__ WOP)
{
    const int r0 = blockIdx.x * 64;
    const int y  = blockIdx.y;
    const float* in; u16* out; int inLD, c0;
    if (y < 128) {
        const int b = y >> 5, ct = y & 31;
        in = x + (size_t)b * CDIM * LDIM; inLD = LDIM; c0 = ct * 64;
        out = XP + (size_t)b * LDIM * CDIM;
    } else if (y < 152) {
        in = wq; inLD = 1536; c0 = (y - 128) * 64; out = WP;
    } else {
        in = wo; inLD = 512;  c0 = (y - 152) * 64; out = WOP;
    }

    __shared__ __align__(16) u16 t[64][80];
    const int tt = threadIdx.x;
    const int lr = tt >> 4, lc = (tt & 15) * 4;
    #pragma unroll
    for (int i = 0; i < 4; ++i) {
        f32x4 v = *(const f32x4*)(in + (size_t)(r0 + lr + i * 16) * inLD + c0 + lc);
        #pragma unroll
        for (int j = 0; j < 4; ++j) t[lc + j][lr + i * 16] = f2b(v[j]);
    }
    __syncthreads();
    // coalesced packed store: wave wvx writes chunk cidx = s*4+wvx contiguously
    const int lane = tt & 63;
    const int wvx = tt >> 6;
    const int qq = lane >> 4, mnq = lane & 15;
    #pragma unroll
    for (int s = 0; s < 2; ++s) {
        const int cidx = s * 4 + wvx;            // 0..7
        const int rt = cidx >> 1, cs = cidx & 1;
        s16x8 v = *(const s16x8*)&t[rt * 16 + mnq][cs * 32 + qq * 8];
        const int slot = ((c0 >> 4) + rt) * 16 + (r0 >> 5) + cs;
        *(s16x8*)(out + (size_t)slot * 512 + lane * 8) = v;
    }
}

// ---------------- QKV GEMM (r12): packed loads; LDS-staged stores; XCD swizzle -
__global__ __launch_bounds__(256)
void qkvgemm_bf16(const u16* __restrict__ XP, const u16* __restrict__ WP,
                  u16* __restrict__ QF, u16* __restrict__ KF, u16* __restrict__ VF)
{
    const int wg = blockIdx.x;
    const int xf = wg >> 6;              // 0..23
    const int yz = wg & 63;              // b*16 + y
    const int b  = yz >> 4;
    const int l0 = (yz & 15) * 128;
    const int f0 = xf * 64;
    const u16* xTb = XP + (size_t)b * LDIM * CDIM;
    const int t = threadIdx.x, w = t >> 6, lane = t & 63;
    const int mn = lane & 15, q = lane >> 4;
    const bool vpart = (f0 >= 1024);

    const u16 *Abase, *Bbase;
    int mbase, nbase;
    if (!vpart) {
        mbase = f0 + (w >> 1) * 32; nbase = l0 + (w & 1) * 64;
        Abase = WP + (size_t)mbase * CDIM; Bbase = xTb + (size_t)nbase * CDIM;
    } else {
        mbase = l0 + w * 32; nbase = f0;
        Abase = xTb + (size_t)mbase * CDIM; Bbase = WP + (size_t)nbase * CDIM;
    }

    f32x4 acc[2][4] = {};
    #pragma unroll 2
    for (int c0 = 0; c0 < CDIM; c0 += 32) {
        s16x8 a[2], bf[4];
        #pragma unroll
        for (int mi = 0; mi < 2; ++mi)
            a[mi] = *(const s16x8*)(Abase + mi * 16 * CDIM + c0 * 16 + lane * 8);
        #pragma unroll
        for (int ni = 0; ni < 4; ++ni)
            bf[ni] = *(const s16x8*)(Bbase + ni * 16 * CDIM + c0 * 16 + lane * 8);
        #pragma unroll
        for (int mi = 0; mi < 2; ++mi)
            #pragma unroll
            for (int ni = 0; ni < 4; ++ni)
                acc[mi][ni] = __builtin_amdgcn_mfma_f32_16x16x32_bf16(a[mi], bf[ni], acc[mi][ni], 0, 0, 0);
    }

    __shared__ __align__(16) u16 stg[8192];      // 16KB staging tile

    if (!vpart) {
        const int part = f0 >> 9;
        const float sc2 = (part == 0) ? 0.18033688f : 1.0f;  // 0.125*log2(e)
        #pragma unroll
        for (int mi = 0; mi < 2; ++mi) {
            const int fg0 = mbase + mi * 16;
            const int d0 = (fg0 & 63) + q * 4;          // 4-aligned d base
            const int kd = d0 >> 5, qq = (d0 >> 3) & 3, e0 = d0 & 7;
            #pragma unroll
            for (int ni = 0; ni < 4; ++ni) {
                const int lg = nbase + ni * 16 + mn;     // L index
                int addr;
                if (part == 0) {                         // QF[t16][kd][lane][8], local
                    const int t16l = (lg & 127) >> 4, mnq = lg & 15;
                    addr = (t16l * 2 + kd) * 512 + (qq * 16 + mnq) * 8 + e0;
                } else {                                 // KF[j64][jt][kd][lane][8], kperm absorbed
                    const int j64l = (lg & 127) >> 6, r6 = lg & 63;
                    const int jt  = ((r6 >> 2) & 1) * 2 + (r6 >> 5);
                    const int mnk = ((r6 >> 3) & 3) * 4 + (r6 & 3);
                    addr = ((j64l * 4 + jt) * 2 + kd) * 512 + (qq * 16 + mnk) * 8 + e0;
                }
                u16x4 pk;
                #pragma unroll
                for (int r = 0; r < 4; ++r) pk[r] = f2b(acc[mi][ni][r] * sc2);
                *(u16x4*)(stg + addr) = pk;
            }
        }
    } else {
        #pragma unroll
        for (int ni = 0; ni < 4; ++ni) {
            const int fg = nbase + ni * 16 + mn;
            const int d = fg & 63;
            const int dt = d >> 4, mnv = d & 15;
            #pragma unroll
            for (int mi = 0; mi < 2; ++mi) {
                const int lg0 = mbase + mi * 16 + q * 4;    // 4-aligned j base
                const int j64l = (lg0 & 127) >> 6, j6 = lg0 & 63;
                const int kj = j6 >> 5, qq = (j6 >> 3) & 3, e0 = j6 & 7;
                const int addr = ((j64l * 2 + kj) * 4 + dt) * 512 + (qq * 16 + mnv) * 8 + e0;
                u16x4 pk;
                #pragma unroll
                for (int r = 0; r < 4; ++r) pk[r] = f2b(acc[mi][ni][r]);
                *(u16x4*)(stg + addr) = pk;
            }
        }
    }

    __syncthreads();
    // linear copy: 4 x (256 threads x 16B) = 16KB, each wave 1KB contiguous
    const int h = (f0 >> 6) & 7;
    const size_t bhoff = (size_t)(b * 8 + h) * LDIM * 64;
    u16* T;
    if (!vpart) {
        const int part = f0 >> 9;
        T = ((part == 0) ? QF + bhoff + (size_t)(l0 >> 4) * 1024
                         : KF + bhoff + (size_t)(l0 >> 6) * 4096);
    } else {
        T = VF + bhoff + (size_t)(l0 >> 6) * 4096;
    }
    #pragma unroll
    for (int it = 0; it < 4; ++it)
        *(s16x8*)(T + it * 2048 + t * 8) = *(const s16x8*)(stg + it * 2048 + t * 8);
}

// ---------------- Flash attention (r5 structure, single dispatch) --------------
// grid (x=bh 32, y=32), 128 threads (2 waves). wg%8 = bh%8: XCD-pinned.
__global__ __launch_bounds__(128)
void attn_k(const u16* __restrict__ QF, const u16* __restrict__ KF,
            const u16* __restrict__ VF, u16* __restrict__ aoP)
{
    const int bh = blockIdx.x;
    const int b = bh >> 3, h = bh & 7;
    const u16* Qh = QF + (size_t)bh * LDIM * 64;
    const u16* Kh = KF + (size_t)bh * LDIM * 64;
    const u16* Vh = VF + (size_t)bh * LDIM * 64;

    __shared__ __align__(16) float o_sh[64][68];   // +4 pad (2-way = free)
    __shared__ float lp_sh[64];

    const int tid = threadIdx.x;
    const int wv = tid >> 6;
    const int lane = tid & 63;
    const int mn = lane & 15, q = lane >> 4;
    const int ib64 = blockIdx.y;         // 64-row i-block
    const int TH = 16;                   // j-tiles per wave (of 32 total)
    const int tbase = wv * TH;

    s16x8 aq[4][2];
    #pragma unroll
    for (int ibt = 0; ibt < 4; ++ibt) {
        const int t16 = ib64 * 4 + ibt;
        #pragma unroll
        for (int kd = 0; kd < 2; ++kd)
            aq[ibt][kd] = *(const s16x8*)(Qh + (size_t)((t16 * 2 + kd) * 512) + lane * 8);
    }

    f32x4 o_acc[4][4] = {};
    float lp[4] = {0.f, 0.f, 0.f, 0.f};

    // preload this wave's tile-0 K/V fragments (fully coalesced)
    s16x8 kc[2][4], vc[2][4];
    {
        const u16* Kt = Kh + (size_t)tbase * 4096;
        const u16* Vt = Vh + (size_t)tbase * 4096;
        #pragma unroll
        for (int kd = 0; kd < 2; ++kd)
            #pragma unroll
            for (int jt = 0; jt < 4; ++jt)
                kc[kd][jt] = *(const s16x8*)(Kt + ((jt * 2 + kd) << 9) + (lane << 3));
        #pragma unroll
        for (int kj = 0; kj < 2; ++kj)
            #pragma unroll
            for (int dt = 0; dt < 4; ++dt)
                vc[kj][dt] = *(const s16x8*)(Vt + ((kj * 4 + dt) << 9) + (lane << 3));
    }

    #pragma unroll 2
    for (int jj = 0; jj < TH; ++jj) {
        const int tn = tbase + ((jj + 1) & (TH - 1));   // last iter wraps (L2-hot)
        const u16* Kt = Kh + (size_t)tn * 4096;
        const u16* Vt = Vh + (size_t)tn * 4096;

        // issue next tile's K loads FIRST
        s16x8 kn[2][4];
        #pragma unroll
        for (int kd = 0; kd < 2; ++kd)
            #pragma unroll
            for (int jt = 0; jt < 4; ++jt)
                kn[kd][jt] = *(const s16x8*)(Kt + ((jt * 2 + kd) << 9) + (lane << 3));

        // S^T = K.Q^T on current K: 32 MFMA (4 ibt)
        f32x4 s[4][4] = {};
        #pragma unroll
        for (int kd = 0; kd < 2; ++kd)
            #pragma unroll
            for (int jt = 0; jt < 4; ++jt)
                #pragma unroll
                for (int ibt = 0; ibt < 4; ++ibt)
                    s[ibt][jt] = __builtin_amdgcn_mfma_f32_16x16x32_bf16(kc[kd][jt], aq[ibt][kd], s[ibt][jt], 0, 0, 0);

        // issue next tile's V loads AFTER QK (staggered: caps VGPR peak)
        s16x8 vn[2][4];
        #pragma unroll
        for (int kj = 0; kj < 2; ++kj)
            #pragma unroll
            for (int dt = 0; dt < 4; ++dt)
                vn[kj][dt] = *(const s16x8*)(Vt + ((kj * 4 + dt) << 9) + (lane << 3));

        // p = 2^s; build PV B-fragments fully in-register (lane-local j-slots).
        #pragma unroll
        for (int kj = 0; kj < 2; ++kj) {
            s16x8 ap[4];
            #pragma unroll
            for (int ibt = 0; ibt < 4; ++ibt) {
                float pa0 = __builtin_amdgcn_exp2f(s[ibt][kj][0]);
                float pa1 = __builtin_amdgcn_exp2f(s[ibt][kj][1]);
                float pa2 = __builtin_amdgcn_exp2f(s[ibt][kj][2]);
                float pa3 = __builtin_amdgcn_exp2f(s[ibt][kj][3]);
                float pb0 = __builtin_amdgcn_exp2f(s[ibt][kj + 2][0]);
                float pb1 = __builtin_amdgcn_exp2f(s[ibt][kj + 2][1]);
                float pb2 = __builtin_amdgcn_exp2f(s[ibt][kj + 2][2]);
                float pb3 = __builtin_amdgcn_exp2f(s[ibt][kj + 2][3]);
                lp[ibt] += ((pa0 + pa1) + (pa2 + pa3)) + ((pb0 + pb1) + (pb2 + pb3));
                union { s16x8 v; u32 w[4]; } u;
                u.w[0] = pk2(pa0, pa1);
                u.w[1] = pk2(pa2, pa3);
                u.w[2] = pk2(pb0, pb1);
                u.w[3] = pk2(pb2, pb3);
                ap[ibt] = u.v;
            }
            #pragma unroll
            for (int dt = 0; dt < 4; ++dt)
                #pragma unroll
                for (int ibt = 0; ibt < 4; ++ibt)
                    o_acc[ibt][dt] = __builtin_amdgcn_mfma_f32_16x16x32_bf16(vc[kj][dt], ap[ibt], o_acc[ibt][dt], 0, 0, 0);
        }

        // rotate prefetched registers
        #pragma unroll
        for (int kd = 0; kd < 2; ++kd)
            #pragma unroll
            for (int jt = 0; jt < 4; ++jt)
                kc[kd][jt] = kn[kd][jt];
        #pragma unroll
        for (int kj = 0; kj < 2; ++kj)
            #pragma unroll
            for (int dt = 0; dt < 4; ++dt)
                vc[kj][dt] = vn[kj][dt];
    }

    #pragma unroll
    for (int ibt = 0; ibt < 4; ++ibt) {
        lp[ibt] += __shfl_xor(lp[ibt], 16);
        lp[ibt] += __shfl_xor(lp[ibt], 32);
    }

    // combine the two waves' j-partials: plain addition (sum-normalized softmax)
    if (wv == 1) {
        #pragma unroll
        for (int ibt = 0; ibt < 4; ++ibt) {
            #pragma unroll
            for (int dt = 0; dt < 4; ++dt)
                *(f32x4*)&o_sh[ibt * 16 + mn][dt * 16 + q * 4] = o_acc[ibt][dt];
            if (q == 0) lp_sh[ibt * 16 + mn] = lp[ibt];
        }
    }
    __syncthreads();
    if (wv == 0) {
        u16* Ab = aoP + (size_t)b * LDIM * 512;
        #pragma unroll
        for (int ibt = 0; ibt < 4; ++ibt) {
            const float rinv = 1.0f / (lp[ibt] + lp_sh[ibt * 16 + mn]);
            const int ltile = ib64 * 4 + ibt;
            #pragma unroll
            for (int dt = 0; dt < 4; ++dt) {
                f32x4 os = *(const f32x4*)&o_sh[ibt * 16 + mn][dt * 16 + q * 4];
                u16x4 pk;
                #pragma unroll
                for (int r = 0; r < 4; ++r)
                    pk[r] = f2b((o_acc[ibt][dt][r] + os[r]) * rinv);
                // packed-chunk store: col = h*64 + dt*16 + q*4 + r
                const int cstep = h * 2 + (dt >> 1);
                const int lanep = ((dt & 1) * 2 + (q >> 1)) * 16 + mn;
                u16* dst = Ab + ((size_t)(ltile * 16 + cstep) * 64 + lanep) * 8 + (q & 1) * 4;
                *(u16x4*)dst = pk;
            }
        }
    }
}

// ---------------- Output GEMM (r13): 32x32 wave tiles (4/SIMD) + XCD swizzle ---
// 1-D grid 1024: wg = xf*128 + (b*32+ly) -> wg%8 = ly%8: aoP sharers co-XCD.
__global__ __launch_bounds__(256)
void outgemm_d(const u16* __restrict__ aoP, const u16* __restrict__ WOP,
               const float* __restrict__ bias, float* __restrict__ Y)
{
    const int wg = blockIdx.x;
    const int xf = wg >> 7;              // 0..7
    const int yz = wg & 127;             // b*32 + ly
    const int b  = yz >> 5;
    const int l0 = (yz & 31) * 64;
    const int f0 = xf * 64;
    const int t = threadIdx.x, w = t >> 6, lane = t & 63;
    const int mn = lane & 15, q = lane >> 4;
    const int mbase = f0 + (w >> 1) * 32;
    const int nbase = l0 + (w & 1) * 32;
    const u16* Abase = WOP + (size_t)mbase * CDIM;
    const u16* Bbase = aoP + ((size_t)b * LDIM + nbase) * CDIM;
    float* Yb = Y + (size_t)b * CDIM * LDIM;

    f32x4 acc[2][2] = {};
    #pragma unroll 2
    for (int c0 = 0; c0 < CDIM; c0 += 32) {
        s16x8 a[2], bf[2];
        #pragma unroll
        for (int mi = 0; mi < 2; ++mi)
            a[mi] = *(const s16x8*)(Abase + mi * 16 * CDIM + c0 * 16 + lane * 8);
        #pragma unroll
        for (int ni = 0; ni < 2; ++ni)
            bf[ni] = *(const s16x8*)(Bbase + ni * 16 * CDIM + c0 * 16 + lane * 8);
        #pragma unroll
        for (int mi = 0; mi < 2; ++mi)
            #pragma unroll
            for (int ni = 0; ni < 2; ++ni)
                acc[mi][ni] = __builtin_amdgcn_mfma_f32_16x16x32_bf16(a[mi], bf[ni], acc[mi][ni], 0, 0, 0);
    }
    #pragma unroll
    for (int mi = 0; mi < 2; ++mi)
        #pragma unroll
        for (int r = 0; r < 4; ++r) {
            const int f = mbase + mi * 16 + q * 4 + r;
            const float bs = bias[f];
            #pragma unroll
            for (int ni = 0; ni < 2; ++ni)
                Yb[(size_t)f * LDIM + nbase + ni * 16 + mn] = acc[mi][ni][r] + bs;
        }
}

extern "C" void kernel_launch(void* const* d_in, const int* in_sizes, int n_in,
                              void* d_out, int out_size, void* d_ws, size_t ws_size,
                              hipStream_t stream) {
    const float *x = nullptr, *w_qkv = nullptr, *w_out = nullptr, *b_out = nullptr;
    for (int i = 0; i < n_in; ++i) {
        switch (in_sizes[i]) {
            case 4 * 512 * 2048: x     = (const float*)d_in[i]; break;
            case 512 * 1536:     w_qkv = (const float*)d_in[i]; break;
            case 512 * 512:      w_out = (const float*)d_in[i]; break;
            case 512:            b_out = (const float*)d_in[i]; break;
        }
    }
    float* out = (float*)d_out;                 // [4][512][2048] f32

    const size_t SLAB = (size_t)BATCH * LDIM * 512;      // 4194304 elems
    u16* WOP = (u16*)d_ws;                               // [512 rows][512] packed
    u16* XP  = WOP + (size_t)512 * 512;                  // [4][2048 rows][512] packed
    u16* WP  = XP + SLAB;                                // [1536 rows][512] packed
    u16* QF  = WP + (size_t)1536 * 512;                  // [32][2048*64] attn-packed
    u16* KF  = QF + SLAB;                                // [32][2048*64] attn-packed
    u16* VF  = KF + SLAB;                                // [32][2048*64] attn-packed
    u16* aoP = VF + SLAB;                                // [4][2048 rows][512] packed

    transpA_k<<<dim3(8, 160), 256, 0, stream>>>(x, w_qkv, w_out, XP, WP, WOP);
    qkvgemm_bf16<<<dim3(1536), 256, 0, stream>>>(XP, WP, QF, KF, VF);
    attn_k<<<dim3(32, 32), 128, 0, stream>>>(QF, KF, VF, aoP);
    outgemm_d<<<dim3(1024), 256, 0, stream>>>(aoP, WOP, b_out, out);
}

// Round 15
// 169.975 us; speedup vs baseline: 1.0762x; 1.0075x over previous
//
#include <hip/hip_runtime.h>

// B=4, C=512, L=2048, H=8, D=64. f32 inputs, f32 output.
// Universal fragment-packed layouts (r4); r11 store coalescing; r12 XCD-reuse
// swizzle (best total: 169.5us). attn: r5 structure, 65.5us, at floor.
// r14 post-mortem: r13's "outgemm -25us" was a top-5 sampling artifact; pool
// is ~105us and qkvgemm (~45-55us, ~270TF) is the main suspect vs its ~15us
// issue-rate model. r15: *** on the exact r12 base: (a) qkv register
// double-buffer prefetch ALONE (r6 confounded it with a retile); (b) transpA
// 1-D grid remap so id%8 = (ct>>1)%8 — xT first-touch writes land on the
// consumer qkv block's XCD L2 (was id%8 = c-range: every read cross-XCD).
// outgemm reverted to r12's 512-block config (r14 proved 1024 neutral). ***

#define LDIM 2048
#define CDIM 512
#define BATCH 4

typedef __attribute__((ext_vector_type(8))) short s16x8;
typedef __attribute__((ext_vector_type(4))) float f32x4;
typedef __attribute__((ext_vector_type(4))) unsigned short u16x4;
typedef unsigned int u32;
typedef unsigned short u16;

__device__ __forceinline__ u16 f2b(float f) {
    unsigned u = __float_as_uint(f);
    u += 0x7fffu + ((u >> 16) & 1u);   // RNE
    return (u16)(u >> 16);
}
// pack two floats -> two bf16 (round-half-up) in one u32 (b in high half)
__device__ __forceinline__ u32 pk2(float a, float b) {
    u32 ua = __float_as_uint(a) + 0x8000u;
    u32 ub = __float_as_uint(b) + 0x8000u;
    return __builtin_amdgcn_perm(ub, ua, 0x07060302u);  // {ub.hi16, ua.hi16}
}

// ---------------- unified transpose + f32->bf16 convert -> packed chunks -------
// 1-D grid 1280. x-part (id<1024): id = (((r0idx*2+v)*4+b)*2+(u>>3))*8+(u&7),
// ct = 2u+v  ->  id%8 = u%8 = (ct>>1)%8 = consumer qkv block's XCD. Weight part
// (id>=1024): plain. Store phase: wave w writes chunk (s*4+w) contiguous (r11).
__global__ __launch_bounds__(256)
void transpA_k(const float* __restrict__ x, const float* __restrict__ wq,
               const float* __restrict__ wo, u16* __restrict__ XP,
               u16* __restrict__ WP, u16* __restrict__ WOP)
{
    const int id = blockIdx.x;
    int r0, y;
    if (id < 1024) {
        const int u  = ((id >> 3) & 1) * 8 + (id & 7);
        const int b  = (id >> 4) & 3;
        const int v  = (id >> 6) & 1;
        r0 = (id >> 7) * 64;
        y  = b * 32 + u * 2 + v;
    } else {
        const int wd = id - 1024;            // 0..255
        r0 = (wd & 7) * 64;
        y  = 128 + (wd >> 3);                // 128..159
    }

    const float* in; u16* out; int inLD, c0;
    if (y < 128) {
        const int b = y >> 5, ct = y & 31;
        in = x + (size_t)b * CDIM * LDIM; inLD = LDIM; c0 = ct * 64;
        out = XP + (size_t)b * LDIM * CDIM;
    } else if (y < 152) {
        in = wq; inLD = 1536; c0 = (y - 128) * 64; out = WP;
    } else {
        in = wo; inLD = 512;  c0 = (y - 152) * 64; out = WOP;
    }

    __shared__ __align__(16) u16 t[64][80];
    const int tt = threadIdx.x;
    const int lr = tt >> 4, lc = (tt & 15) * 4;
    #pragma unroll
    for (int i = 0; i < 4; ++i) {
        f32x4 v = *(const f32x4*)(in + (size_t)(r0 + lr + i * 16) * inLD + c0 + lc);
        #pragma unroll
        for (int j = 0; j < 4; ++j) t[lc + j][lr + i * 16] = f2b(v[j]);
    }
    __syncthreads();
    // coalesced packed store: wave wvx writes chunk cidx = s*4+wvx contiguously
    const int lane = tt & 63;
    const int wvx = tt >> 6;
    const int qq = lane >> 4, mnq = lane & 15;
    #pragma unroll
    for (int s = 0; s < 2; ++s) {
        const int cidx = s * 4 + wvx;            // 0..7
        const int rt = cidx >> 1, cs = cidx & 1;
        s16x8 v = *(const s16x8*)&t[rt * 16 + mnq][cs * 32 + qq * 8];
        const int slot = ((c0 >> 4) + rt) * 16 + (r0 >> 5) + cs;
        *(s16x8*)(out + (size_t)slot * 512 + lane * 8) = v;
    }
}

// ---------------- QKV GEMM: r12 structure + register double-buffer prefetch ----
// 1-D grid 1536: wg = xf*64 + (b*16+y) -> wg%8 = y%8 (xT sharers co-XCD).
__global__ __launch_bounds__(256)
void qkvgemm_bf16(const u16* __restrict__ XP, const u16* __restrict__ WP,
                  u16* __restrict__ QF, u16* __restrict__ KF, u16* __restrict__ VF)
{
    const int wg = blockIdx.x;
    const int xf = wg >> 6;              // 0..23
    const int yz = wg & 63;              // b*16 + y
    const int b  = yz >> 4;
    const int l0 = (yz & 15) * 128;
    const int f0 = xf * 64;
    const u16* xTb = XP + (size_t)b * LDIM * CDIM;
    const int t = threadIdx.x, w = t >> 6, lane = t & 63;
    const int mn = lane & 15, q = lane >> 4;
    const bool vpart = (f0 >= 1024);

    const u16 *Abase, *Bbase;
    int mbase, nbase;
    if (!vpart) {
        mbase = f0 + (w >> 1) * 32; nbase = l0 + (w & 1) * 64;
        Abase = WP + (size_t)mbase * CDIM; Bbase = xTb + (size_t)nbase * CDIM;
    } else {
        mbase = l0 + w * 32; nbase = f0;
        Abase = xTb + (size_t)mbase * CDIM; Bbase = WP + (size_t)nbase * CDIM;
    }

    f32x4 acc[2][4] = {};
    s16x8 a[2], bf[4], an[2], bn[4];
    #pragma unroll
    for (int mi = 0; mi < 2; ++mi)
        a[mi] = *(const s16x8*)(Abase + mi * 16 * CDIM + lane * 8);
    #pragma unroll
    for (int ni = 0; ni < 4; ++ni)
        bf[ni] = *(const s16x8*)(Bbase + ni * 16 * CDIM + lane * 8);

    for (int c0 = 0; c0 < CDIM; c0 += 32) {
        const int cn = (c0 + 32) & (CDIM - 1);   // last iter wraps (L2-hot)
        #pragma unroll
        for (int mi = 0; mi < 2; ++mi)
            an[mi] = *(const s16x8*)(Abase + mi * 16 * CDIM + cn * 16 + lane * 8);
        #pragma unroll
        for (int ni = 0; ni < 4; ++ni)
            bn[ni] = *(const s16x8*)(Bbase + ni * 16 * CDIM + cn * 16 + lane * 8);
        #pragma unroll
        for (int mi = 0; mi < 2; ++mi)
            #pragma unroll
            for (int ni = 0; ni < 4; ++ni)
                acc[mi][ni] = __builtin_amdgcn_mfma_f32_16x16x32_bf16(a[mi], bf[ni], acc[mi][ni], 0, 0, 0);
        #pragma unroll
        for (int mi = 0; mi < 2; ++mi) a[mi] = an[mi];
        #pragma unroll
        for (int ni = 0; ni < 4; ++ni) bf[ni] = bn[ni];
    }

    __shared__ __align__(16) u16 stg[8192];      // 16KB staging tile

    if (!vpart) {
        const int part = f0 >> 9;
        const float sc2 = (part == 0) ? 0.18033688f : 1.0f;  // 0.125*log2(e)
        #pragma unroll
        for (int mi = 0; mi < 2; ++mi) {
            const int fg0 = mbase + mi * 16;
            const int d0 = (fg0 & 63) + q * 4;          // 4-aligned d base
            const int kd = d0 >> 5, qq = (d0 >> 3) & 3, e0 = d0 & 7;
            #pragma unroll
            for (int ni = 0; ni < 4; ++ni) {
                const int lg = nbase + ni * 16 + mn;     // L index
                int addr;
                if (part == 0) {                         // QF[t16][kd][lane][8], local
                    const int t16l = (lg & 127) >> 4, mnq = lg & 15;
                    addr = (t16l * 2 + kd) * 512 + (qq * 16 + mnq) * 8 + e0;
                } else {                                 // KF[j64][jt][kd][lane][8], kperm absorbed
                    const int j64l = (lg & 127) >> 6, r6 = lg & 63;
                    const int jt  = ((r6 >> 2) & 1) * 2 + (r6 >> 5);
                    const int mnk = ((r6 >> 3) & 3) * 4 + (r6 & 3);
                    addr = ((j64l * 4 + jt) * 2 + kd) * 512 + (qq * 16 + mnk) * 8 + e0;
                }
                u16x4 pk;
                #pragma unroll
                for (int r = 0; r < 4; ++r) pk[r] = f2b(acc[mi][ni][r] * sc2);
                *(u16x4*)(stg + addr) = pk;
            }
        }
    } else {
        #pragma unroll
        for (int ni = 0; ni < 4; ++ni) {
            const int fg = nbase + ni * 16 + mn;
            const int d = fg & 63;
            const int dt = d >> 4, mnv = d & 15;
            #pragma unroll
            for (int mi = 0; mi < 2; ++mi) {
                const int lg0 = mbase + mi * 16 + q * 4;    // 4-aligned j base
                const int j64l = (lg0 & 127) >> 6, j6 = lg0 & 63;
                const int kj = j6 >> 5, qq = (j6 >> 3) & 3, e0 = j6 & 7;
                const int addr = ((j64l * 2 + kj) * 4 + dt) * 512 + (qq * 16 + mnv) * 8 + e0;
                u16x4 pk;
                #pragma unroll
                for (int r = 0; r < 4; ++r) pk[r] = f2b(acc[mi][ni][r]);
                *(u16x4*)(stg + addr) = pk;
            }
        }
    }

    __syncthreads();
    // linear copy: 4 x (256 threads x 16B) = 16KB, each wave 1KB contiguous
    const int h = (f0 >> 6) & 7;
    const size_t bhoff = (size_t)(b * 8 + h) * LDIM * 64;
    u16* T;
    if (!vpart) {
        const int part = f0 >> 9;
        T = ((part == 0) ? QF + bhoff + (size_t)(l0 >> 4) * 1024
                         : KF + bhoff + (size_t)(l0 >> 6) * 4096);
    } else {
        T = VF + bhoff + (size_t)(l0 >> 6) * 4096;
    }
    #pragma unroll
    for (int it = 0; it < 4; ++it)
        *(s16x8*)(T + it * 2048 + t * 8) = *(const s16x8*)(stg + it * 2048 + t * 8);
}

// ---------------- Flash attention (r5 structure, single dispatch) --------------
// grid (x=bh 32, y=32), 128 threads (2 waves). wg%8 = bh%8: XCD-pinned.
__global__ __launch_bounds__(128)
void attn_k(const u16* __restrict__ QF, const u16* __restrict__ KF,
            const u16* __restrict__ VF, u16* __restrict__ aoP)
{
    const int bh = blockIdx.x;
    const int b = bh >> 3, h = bh & 7;
    const u16* Qh = QF + (size_t)bh * LDIM * 64;
    const u16* Kh = KF + (size_t)bh * LDIM * 64;
    const u16* Vh = VF + (size_t)bh * LDIM * 64;

    __shared__ __align__(16) float o_sh[64][68];   // +4 pad (2-way = free)
    __shared__ float lp_sh[64];

    const int tid = threadIdx.x;
    const int wv = tid >> 6;
    const int lane = tid & 63;
    const int mn = lane & 15, q = lane >> 4;
    const int ib64 = blockIdx.y;         // 64-row i-block
    const int TH = 16;                   // j-tiles per wave (of 32 total)
    const int tbase = wv * TH;

    s16x8 aq[4][2];
    #pragma unroll
    for (int ibt = 0; ibt < 4; ++ibt) {
        const int t16 = ib64 * 4 + ibt;
        #pragma unroll
        for (int kd = 0; kd < 2; ++kd)
            aq[ibt][kd] = *(const s16x8*)(Qh + (size_t)((t16 * 2 + kd) * 512) + lane * 8);
    }

    f32x4 o_acc[4][4] = {};
    float lp[4] = {0.f, 0.f, 0.f, 0.f};

    // preload this wave's tile-0 K/V fragments (fully coalesced)
    s16x8 kc[2][4], vc[2][4];
    {
        const u16* Kt = Kh + (size_t)tbase * 4096;
        const u16* Vt = Vh + (size_t)tbase * 4096;
        #pragma unroll
        for (int kd = 0; kd < 2; ++kd)
            #pragma unroll
            for (int jt = 0; jt < 4; ++jt)
                kc[kd][jt] = *(const s16x8*)(Kt + ((jt * 2 + kd) << 9) + (lane << 3));
        #pragma unroll
        for (int kj = 0; kj < 2; ++kj)
            #pragma unroll
            for (int dt = 0; dt < 4; ++dt)
                vc[kj][dt] = *(const s16x8*)(Vt + ((kj * 4 + dt) << 9) + (lane << 3));
    }

    #pragma unroll 2
    for (int jj = 0; jj < TH; ++jj) {
        const int tn = tbase + ((jj + 1) & (TH - 1));   // last iter wraps (L2-hot)
        const u16* Kt = Kh + (size_t)tn * 4096;
        const u16* Vt = Vh + (size_t)tn * 4096;

        // issue next tile's K loads FIRST
        s16x8 kn[2][4];
        #pragma unroll
        for (int kd = 0; kd < 2; ++kd)
            #pragma unroll
            for (int jt = 0; jt < 4; ++jt)
                kn[kd][jt] = *(const s16x8*)(Kt + ((jt * 2 + kd) << 9) + (lane << 3));

        // S^T = K.Q^T on current K: 32 MFMA (4 ibt)
        f32x4 s[4][4] = {};
        #pragma unroll
        for (int kd = 0; kd < 2; ++kd)
            #pragma unroll
            for (int jt = 0; jt < 4; ++jt)
                #pragma unroll
                for (int ibt = 0; ibt < 4; ++ibt)
                    s[ibt][jt] = __builtin_amdgcn_mfma_f32_16x16x32_bf16(kc[kd][jt], aq[ibt][kd], s[ibt][jt], 0, 0, 0);

        // issue next tile's V loads AFTER QK (staggered: caps VGPR peak)
        s16x8 vn[2][4];
        #pragma unroll
        for (int kj = 0; kj < 2; ++kj)
            #pragma unroll
            for (int dt = 0; dt < 4; ++dt)
                vn[kj][dt] = *(const s16x8*)(Vt + ((kj * 4 + dt) << 9) + (lane << 3));

        // p = 2^s; build PV B-fragments fully in-register (lane-local j-slots).
        #pragma unroll
        for (int kj = 0; kj < 2; ++kj) {
            s16x8 ap[4];
            #pragma unroll
            for (int ibt = 0; ibt < 4; ++ibt) {
                float pa0 = __builtin_amdgcn_exp2f(s[ibt][kj][0]);
                float pa1 = __builtin_amdgcn_exp2f(s[ibt][kj][1]);
                float pa2 = __builtin_amdgcn_exp2f(s[ibt][kj][2]);
                float pa3 = __builtin_amdgcn_exp2f(s[ibt][kj][3]);
                float pb0 = __builtin_amdgcn_exp2f(s[ibt][kj + 2][0]);
                float pb1 = __builtin_amdgcn_exp2f(s[ibt][kj + 2][1]);
                float pb2 = __builtin_amdgcn_exp2f(s[ibt][kj + 2][2]);
                float pb3 = __builtin_amdgcn_exp2f(s[ibt][kj + 2][3]);
                lp[ibt] += ((pa0 + pa1) + (pa2 + pa3)) + ((pb0 + pb1) + (pb2 + pb3));
                union { s16x8 v; u32 w[4]; } u;
                u.w[0] = pk2(pa0, pa1);
                u.w[1] = pk2(pa2, pa3);
                u.w[2] = pk2(pb0, pb1);
                u.w[3] = pk2(pb2, pb3);
                ap[ibt] = u.v;
            }
            #pragma unroll
            for (int dt = 0; dt < 4; ++dt)
                #pragma unroll
                for (int ibt = 0; ibt < 4; ++ibt)
                    o_acc[ibt][dt] = __builtin_amdgcn_mfma_f32_16x16x32_bf16(vc[kj][dt], ap[ibt], o_acc[ibt][dt], 0, 0, 0);
        }

        // rotate prefetched registers
        #pragma unroll
        for (int kd = 0; kd < 2; ++kd)
            #pragma unroll
            for (int jt = 0; jt < 4; ++jt)
                kc[kd][jt] = kn[kd][jt];
        #pragma unroll
        for (int kj = 0; kj < 2; ++kj)
            #pragma unroll
            for (int dt = 0; dt < 4; ++dt)
                vc[kj][dt] = vn[kj][dt];
    }

    #pragma unroll
    for (int ibt = 0; ibt < 4; ++ibt) {
        lp[ibt] += __shfl_xor(lp[ibt], 16);
        lp[ibt] += __shfl_xor(lp[ibt], 32);
    }

    // combine the two waves' j-partials: plain addition (sum-normalized softmax)
    if (wv == 1) {
        #pragma unroll
        for (int ibt = 0; ibt < 4; ++ibt) {
            #pragma unroll
            for (int dt = 0; dt < 4; ++dt)
                *(f32x4*)&o_sh[ibt * 16 + mn][dt * 16 + q * 4] = o_acc[ibt][dt];
            if (q == 0) lp_sh[ibt * 16 + mn] = lp[ibt];
        }
    }
    __syncthreads();
    if (wv == 0) {
        u16* Ab = aoP + (size_t)b * LDIM * 512;
        #pragma unroll
        for (int ibt = 0; ibt < 4; ++ibt) {
            const float rinv = 1.0f / (lp[ibt] + lp_sh[ibt * 16 + mn]);
            const int ltile = ib64 * 4 + ibt;
            #pragma unroll
            for (int dt = 0; dt < 4; ++dt) {
                f32x4 os = *(const f32x4*)&o_sh[ibt * 16 + mn][dt * 16 + q * 4];
                u16x4 pk;
                #pragma unroll
                for (int r = 0; r < 4; ++r)
                    pk[r] = f2b((o_acc[ibt][dt][r] + os[r]) * rinv);
                // packed-chunk store: col = h*64 + dt*16 + q*4 + r
                const int cstep = h * 2 + (dt >> 1);
                const int lanep = ((dt & 1) * 2 + (q >> 1)) * 16 + mn;
                u16* dst = Ab + ((size_t)(ltile * 16 + cstep) * 64 + lanep) * 8 + (q & 1) * 4;
                *(u16x4*)dst = pk;
            }
        }
    }
}

// ---------------- Output GEMM (r12 config): packed loads + XCD swizzle ---------
// 1-D grid 512: wg = xf*64 + (b*16+y) -> wg%8 = y%8: aoP B-tile sharers co-XCD.
__global__ __launch_bounds__(256)
void outgemm_d(const u16* __restrict__ aoP, const u16* __restrict__ WOP,
               const float* __restrict__ bias, float* __restrict__ Y)
{
    const int wg = blockIdx.x;
    const int xf = wg >> 6;              // 0..7
    const int yz = wg & 63;              // b*16 + y
    const int b  = yz >> 4;
    const int l0 = (yz & 15) * 128;
    const int f0 = xf * 64;
    const int t = threadIdx.x, w = t >> 6, lane = t & 63;
    const int mn = lane & 15, q = lane >> 4;
    const int mbase = f0 + (w >> 1) * 32;
    const int nbase = l0 + (w & 1) * 64;
    const u16* Abase = WOP + (size_t)mbase * CDIM;
    const u16* Bbase = aoP + ((size_t)b * LDIM + nbase) * CDIM;
    float* Yb = Y + (size_t)b * CDIM * LDIM;

    f32x4 acc[2][4] = {};
    #pragma unroll 2
    for (int c0 = 0; c0 < CDIM; c0 += 32) {
        s16x8 a[2], bf[4];
        #pragma unroll
        for (int mi = 0; mi < 2; ++mi)
            a[mi] = *(const s16x8*)(Abase + mi * 16 * CDIM + c0 * 16 + lane * 8);
        #pragma unroll
        for (int ni = 0; ni < 4; ++ni)
            bf[ni] = *(const s16x8*)(Bbase + ni * 16 * CDIM + c0 * 16 + lane * 8);
        #pragma unroll
        for (int mi = 0; mi < 2; ++mi)
            #pragma unroll
            for (int ni = 0; ni < 4; ++ni)
                acc[mi][ni] = __builtin_amdgcn_mfma_f32_16x16x32_bf16(a[mi], bf[ni], acc[mi][ni], 0, 0, 0);
    }
    #pragma unroll
    for (int mi = 0; mi < 2; ++mi)
        #pragma unroll
        for (int r = 0; r < 4; ++r) {
            const int f = mbase + mi * 16 + q * 4 + r;
            const float bs = bias[f];
            #pragma unroll
            for (int ni = 0; ni < 4; ++ni)
                Yb[(size_t)f * LDIM + nbase + ni * 16 + mn] = acc[mi][ni][r] + bs;
        }
}

extern "C" void kernel_launch(void* const* d_in, const int* in_sizes, int n_in,
                              void* d_out, int out_size, void* d_ws, size_t ws_size,
                              hipStream_t stream) {
    const float *x = nullptr, *w_qkv = nullptr, *w_out = nullptr, *b_out = nullptr;
    for (int i = 0; i < n_in; ++i) {
        switch (in_sizes[i]) {
            case 4 * 512 * 2048: x     = (const float*)d_in[i]; break;
            case 512 * 1536:     w_qkv = (const float*)d_in[i]; break;
            case 512 * 512:      w_out = (const float*)d_in[i]; break;
            case 512:            b_out = (const float*)d_in[i]; break;
        }
    }
    float* out = (float*)d_out;                 // [4][512][2048] f32

    const size_t SLAB = (size_t)BATCH * LDIM * 512;      // 4194304 elems
    u16* WOP = (u16*)d_ws;                               // [512 rows][512] packed
    u16* XP  = WOP + (size_t)512 * 512;                  // [4][2048 rows][512] packed
    u16* WP  = XP + SLAB;                                // [1536 rows][512] packed
    u16* QF  = WP + (size_t)1536 * 512;                  // [32][2048*64] attn-packed
    u16* KF  = QF + SLAB;                                // [32][2048*64] attn-packed
    u16* VF  = KF + SLAB;                                // [32][2048*64] attn-packed
    u16* aoP = VF + SLAB;                                // [4][2048 rows][512] packed

    transpA_k<<<dim3(1280), 256, 0, stream>>>(x, w_qkv, w_out, XP, WP, WOP);
    qkvgemm_bf16<<<dim3(1536), 256, 0, stream>>>(XP, WP, QF, KF, VF);
    attn_k<<<dim3(32, 32), 128, 0, stream>>>(QF, KF, VF, aoP);
    outgemm_d<<<dim3(512), 256, 0, stream>>>(aoP, WOP, b_out, out);
}